// Round 2
// baseline (337.195 us; speedup 1.0000x reference)
//
#include <hip/hip_runtime.h>
#include <hip/hip_bf16.h>

// B=8, CIN=512, COUT=512, RES=64, WDIM=512, K=3, GROUPS=32
typedef short short8 __attribute__((ext_vector_type(8)));
typedef float f32x4 __attribute__((ext_vector_type(4)));

#define SWZ(c) (((c) & 3) ^ (((c) >> 2) & 3))

static __device__ __forceinline__ unsigned short f2bf(float f) {
    union { float f; unsigned u; } v; v.f = f;
    unsigned r = v.u + 0x7FFFu + ((v.u >> 16) & 1u);
    return (unsigned short)(r >> 16);
}

static __device__ __forceinline__ void gload16(const void* g, void* l) {
    __builtin_amdgcn_global_load_lds(
        (const __attribute__((address_space(1))) unsigned int*)g,
        (__attribute__((address_space(3))) unsigned int*)l, 16, 0, 0);
}

// ---------------- styles: s = w @ (affW^T/sqrt(512)) + affb; st = m1*m2+m3 ----
__global__ __launch_bounds__(256) void stylesk(
    const float* __restrict__ w, const float* __restrict__ affW,
    const float* __restrict__ affb, float* __restrict__ styles)
{
    int ch = blockIdx.x, b = blockIdx.y;
    int lane = threadIdx.x & 63, wv = threadIdx.x >> 6;
    float wr[8];
    const float* wb = w + b * 512 + lane * 8;
#pragma unroll
    for (int r = 0; r < 8; ++r) wr[r] = wb[r];
    for (int ii = 0; ii < 16; ++ii) {
        int i = ch * 64 + wv * 16 + ii;
        float d[3];
#pragma unroll
        for (int jj = 0; jj < 3; ++jj) {
            const float* a = affW + (size_t)(jj * 512 + i) * 512 + lane * 8;
            float dd = 0.f;
#pragma unroll
            for (int r = 0; r < 8; ++r) dd += wr[r] * a[r];
            for (int off = 32; off; off >>= 1) dd += __shfl_xor(dd, off);
            d[jj] = dd;
        }
        if (lane == 0) {
            const float inv = 0.044194173824159216f; // 1/sqrt(512)
            float s0 = d[0] * inv + affb[i];
            float s1 = d[1] * inv + affb[512 + i];
            float s2 = d[2] * inv + affb[1024 + i];
            styles[b * 512 + i] = s0 * s1 + s2;
        }
    }
}

// ---------------- GroupNorm stats: one block per (b,group) -------------------
__global__ __launch_bounds__(256) void gnstats(
    const float* __restrict__ x, float* __restrict__ meanv, float* __restrict__ rstdv)
{
    int bx = blockIdx.x, t = threadIdx.x;
    const float4* p = (const float4*)(x + (size_t)bx * 65536);
    float s = 0.f, q = 0.f;
#pragma unroll 4
    for (int k = 0; k < 64; ++k) {
        float4 v = p[t + (k << 8)];
        s += v.x + v.y + v.z + v.w;
        q += v.x * v.x + v.y * v.y + v.z * v.z + v.w * v.w;
    }
    for (int off = 32; off; off >>= 1) { s += __shfl_xor(s, off); q += __shfl_xor(q, off); }
    __shared__ float rs[4], rq[4];
    if ((t & 63) == 0) { rs[t >> 6] = s; rq[t >> 6] = q; }
    __syncthreads();
    if (t == 0) {
        float S = rs[0] + rs[1] + rs[2] + rs[3];
        float Q = rq[0] + rq[1] + rq[2] + rq[3];
        float mu = S * (1.f / 65536.f);
        float var = Q * (1.f / 65536.f) - mu * mu;
        meanv[bx] = mu;
        rstdv[bx] = rsqrtf(var + 1e-5f);
    }
}

// ---------------- demod coefficients: block per co ---------------------------
__global__ __launch_bounds__(256) void dcoefk(
    const float* __restrict__ weight, const float* __restrict__ styles,
    float* __restrict__ dcoef)
{
    __shared__ float st2[8 * 512];
    __shared__ float red[32];
    int co = blockIdx.x, t = threadIdx.x;
    for (int i = t; i < 4096; i += 256) { float s = styles[i]; st2[i] = s * s; }
    __syncthreads();
    float p[8] = {0, 0, 0, 0, 0, 0, 0, 0};
#pragma unroll
    for (int half = 0; half < 2; ++half) {
        int ci = t * 2 + half;
        const float* wp = weight + ((size_t)co * 512 + ci) * 9;
        float wsq = 0.f;
#pragma unroll
        for (int k = 0; k < 9; ++k) wsq += wp[k] * wp[k];
#pragma unroll
        for (int b = 0; b < 8; ++b) p[b] += wsq * st2[b * 512 + ci];
    }
    int lane = t & 63, wv = t >> 6;
#pragma unroll
    for (int b = 0; b < 8; ++b) {
        float v = p[b];
        for (int off = 32; off; off >>= 1) v += __shfl_xor(v, off);
        if (lane == 0) red[wv * 8 + b] = v;
    }
    __syncthreads();
    if (t < 8) {
        float s = red[t] + red[8 + t] + red[16 + t] + red[24 + t];
        dcoef[t * 512 + co] = rsqrtf(s + 1e-8f);
    }
}

// ---------------- weight pack: [co][ci][3][3] f32 -> [co][tap][ci] bf16 ------
__global__ __launch_bounds__(256) void packk(
    const float* __restrict__ weight, unsigned short* __restrict__ wpk)
{
    __shared__ float ld[9 * 128];
    int co = blockIdx.x, c4 = blockIdx.y, t = threadIdx.x;
    const float* src = weight + (size_t)co * 4608 + c4 * 1152;
    for (int f = t; f < 1152; f += 256)
        ld[(f % 9) * 128 + (f / 9)] = src[f];
    __syncthreads();
    unsigned short* dst = wpk + (size_t)co * 4608 + c4 * 128;
    for (int f = t; f < 1152; f += 256) {
        int tap = f >> 7, ci = f & 127;
        dst[tap * 512 + ci] = f2bf(ld[tap * 128 + ci]);
    }
}

// ------- normalize + modulate + transpose to channel-last bf16 ---------------
// xm[b][pix][ci] = ((x - mu)*rstd*gnw + gnb) * styles  (bf16)
__global__ __launch_bounds__(256) void modpack(
    const float* __restrict__ x, const float* __restrict__ styles,
    const float* __restrict__ gnw, const float* __restrict__ gnb,
    const float* __restrict__ meanv, const float* __restrict__ rstdv,
    unsigned short* __restrict__ xm)
{
    __shared__ float sA[512], sB[512];
    __shared__ unsigned short tr[32 * 520];
    int t = threadIdx.x;
    int px0 = blockIdx.x * 32, b = blockIdx.y;
    for (int i = t; i < 512; i += 256) {
        int g = i >> 4;
        float mu = meanv[b * 32 + g], r = rstdv[b * 32 + g];
        float st = styles[b * 512 + i];
        float a = r * gnw[i];
        sA[i] = a * st;
        sB[i] = (gnb[i] - mu * a) * st;
    }
    __syncthreads();
    int p = t & 31, cb = t >> 5;
    const float* xb = x + (size_t)b * 512 * 4096 + px0 + p;
#pragma unroll 4
    for (int it = 0; it < 64; ++it) {
        int ci = cb + (it << 3);
        float v = xb[(size_t)ci * 4096];
        tr[p * 520 + ci] = f2bf(v * sA[ci] + sB[ci]);
    }
    __syncthreads();
    int gran = t & 63;
#pragma unroll
    for (int k = 0; k < 8; ++k) {
        int pl = k * 4 + (t >> 6);
        short8 v = *(const short8*)&tr[pl * 520 + gran * 8];
        *(short8*)&xm[((size_t)(b * 4096 + px0 + pl) << 9) + gran * 8] = v;
    }
}

// ---------------- implicit-GEMM 3x3 conv + full epilogue ---------------------
__global__ __launch_bounds__(256, 2) void conv3(
    const unsigned short* __restrict__ xm, const unsigned short* __restrict__ wpk,
    const unsigned short* __restrict__ zp,
    const float* __restrict__ x, const float* __restrict__ noise,
    const float* __restrict__ bias, const float* __restrict__ gnw,
    const float* __restrict__ gnb, const float* __restrict__ gamma,
    const float* __restrict__ dcoef, const float* __restrict__ meanv,
    const float* __restrict__ rstdv, const float* __restrict__ nsp,
    float* __restrict__ out)
{
    __shared__ unsigned short in_lds[4 * 66 * 32];   // [r][c 0..65][ci32]  16.9KB
    __shared__ unsigned short w_lds[3 * 128 * 32];   // [dx][co128][ci32]   24.6KB
    const int tid = threadIdx.x, lane = tid & 63, wv = tid >> 6;
    const int ct = blockIdx.x, pt = blockIdx.y, b = blockIdx.z;
    const int co0 = ct * 128;
    const int wm = wv >> 1, wn = wv & 1;
    const int lm = lane & 15, lg = lane >> 4;

    // zero halo columns c=0 and c=65 (never overwritten afterwards)
    if (tid < 32) {
        int r = tid >> 3, cI = ((tid >> 2) & 1) * 65, g = tid & 3;
        *(short8*)((char*)in_lds + r * 4224 + cI * 64 + g * 16) = (short8)0;
    }

    const int h0 = pt * 2;
    const int imgrow = h0 - 1 + wv;           // wave wv stages LDS row wv
    const bool rowok = (unsigned)imgrow < 64u;
    const unsigned short* isrc[4];
    char* idst[4];
#pragma unroll
    for (int q = 0; q < 4; ++q) {
        int lin = q * 64 + lane;
        int c1 = lin >> 2, g = lin & 3;
        int gs = g ^ SWZ(c1 + 1);
        isrc[q] = xm + (((size_t)(b * 4096 + imgrow * 64 + c1)) << 9) + gs * 8;
        idst[q] = (char*)in_lds + wv * 4224 + 64 + q * 1024;
    }
    const unsigned short* wsrc[6];
    char* wdst[6];
#pragma unroll
    for (int j = 0; j < 6; ++j) {
        int gid = wv * 384 + j * 64 + lane;
        int dx = gid >> 9, co = (gid >> 2) & 127, g = gid & 3;
        wsrc[j] = wpk + (size_t)(co0 + co) * 4608 + dx * 512 + (g ^ SWZ(co)) * 8;
        wdst[j] = (char*)w_lds + (wv * 384 + j * 64) * 16;
    }

    f32x4 acc[4][4];
#pragma unroll
    for (int m = 0; m < 4; ++m)
#pragma unroll
        for (int n = 0; n < 4; ++n) acc[m][n] = (f32x4){0.f, 0.f, 0.f, 0.f};

    for (int cc = 0; cc < 16; ++cc) {
        __syncthreads();   // previous iteration's reads done
#pragma unroll
        for (int q = 0; q < 4; ++q)
            gload16(rowok ? (const void*)(isrc[q] + cc * 32) : (const void*)zp, idst[q]);
#pragma unroll
        for (int dy = 0; dy < 3; ++dy) {
            if (dy) __syncthreads();   // w_lds reads of prev dy done
#pragma unroll
            for (int j = 0; j < 6; ++j)
                gload16(wsrc[j] + dy * 1536 + cc * 32, wdst[j]);
            __syncthreads();           // staged data visible (vmcnt drained)
#pragma unroll
            for (int dx = 0; dx < 3; ++dx) {
                short8 af[4], bf[4];
#pragma unroll
                for (int m = 0; m < 4; ++m) {
                    int col = wm * 64 + m * 16 + lm;
                    af[m] = *(const short8*)((char*)w_lds +
                            (dx * 128 + col) * 64 + (lg ^ SWZ(col)) * 16);
                }
#pragma unroll
                for (int n = 0; n < 4; ++n) {
                    int c = n * 16 + lm + dx;
                    bf[n] = *(const short8*)((char*)in_lds +
                            (wn + dy) * 4224 + c * 64 + (lg ^ SWZ(c)) * 16);
                }
#pragma unroll
                for (int m = 0; m < 4; ++m)
#pragma unroll
                    for (int n = 0; n < 4; ++n)
                        acc[m][n] = __builtin_amdgcn_mfma_f32_16x16x32_bf16(
                            af[m], bf[n], acc[m][n], 0, 0, 0);
            }
        }
    }

    // epilogue: demod, noise, bias, lrelu*2*sqrt(2), layer-scale, residual, *sqrt(2)
    const float nsv = *nsp;
#pragma unroll
    for (int m = 0; m < 4; ++m) {
#pragma unroll
        for (int n = 0; n < 4; ++n) {
            int pix = pt * 128 + wn * 64 + n * 16 + lm;
            float nz = noise[b * 4096 + pix] * nsv;
#pragma unroll
            for (int j = 0; j < 4; ++j) {
                int co = co0 + wm * 64 + m * 16 + lg * 4 + j;
                int gidx = co >> 4;
                float v = acc[m][n][j] * dcoef[b * 512 + co] + nz + bias[co];
                float act = (v > 0.f ? v : 0.2f * v) * 2.8284271247461903f;
                float xv = x[((size_t)(b * 512 + co)) * 4096 + pix];
                float xn = (xv - meanv[b * 32 + gidx]) * rstdv[b * 32 + gidx] * gnw[co] + gnb[co];
                out[((size_t)(b * 512 + co)) * 4096 + pix] =
                    (gamma[co] * act + xn) * 1.4142135623730951f;
            }
        }
    }
}

extern "C" void kernel_launch(void* const* d_in, const int* in_sizes, int n_in,
                              void* d_out, int out_size, void* d_ws, size_t ws_size,
                              hipStream_t stream) {
    const float* x      = (const float*)d_in[0];
    const float* w      = (const float*)d_in[1];
    const float* noise  = (const float*)d_in[2];
    const float* weight = (const float*)d_in[3];
    const float* bias   = (const float*)d_in[4];
    const float* affW   = (const float*)d_in[5];
    const float* affb   = (const float*)d_in[6];
    const float* gnw    = (const float*)d_in[7];
    const float* gnb    = (const float*)d_in[8];
    const float* gamma  = (const float*)d_in[9];
    const float* nsp    = (const float*)d_in[10];
    float* out = (float*)d_out;

    char* ws = (char*)d_ws;
    float* styles = (float*)(ws + 0);            // 16384 B
    float* dcoef  = (float*)(ws + 16384);        // 16384 B
    float* meanv  = (float*)(ws + 32768);        // 1024 B
    float* rstdv  = (float*)(ws + 33792);        // 1024 B
    unsigned short* zp  = (unsigned short*)(ws + 34816);   // 4096 B zero page
    unsigned short* wpk = (unsigned short*)(ws + 38912);   // 4,718,592 B
    unsigned short* xm  = (unsigned short*)(ws + 4757504); // 33,554,432 B

    hipMemsetAsync(zp, 0, 4096, stream);

    stylesk<<<dim3(8, 8), 256, 0, stream>>>(w, affW, affb, styles);
    gnstats<<<dim3(256), 256, 0, stream>>>(x, meanv, rstdv);
    packk<<<dim3(512, 4), 256, 0, stream>>>(weight, wpk);
    dcoefk<<<dim3(512), 256, 0, stream>>>(weight, styles, dcoef);
    modpack<<<dim3(128, 8), 256, 0, stream>>>(x, styles, gnw, gnb, meanv, rstdv, xm);
    conv3<<<dim3(4, 32, 8), 256, 0, stream>>>(xm, wpk, zp, x, noise, bias, gnw, gnb,
                                              gamma, dcoef, meanv, rstdv, nsp, out);
}

// Round 3
// 309.509 us; speedup vs baseline: 1.0895x; 1.0895x over previous
//
#include <hip/hip_runtime.h>
#include <hip/hip_bf16.h>

// B=8, CIN=512, COUT=512, RES=64, WDIM=512, K=3, GROUPS=32
typedef short short8 __attribute__((ext_vector_type(8)));
typedef float f32x4 __attribute__((ext_vector_type(4)));

#define SWZ(c) (((c) & 3) ^ (((c) >> 2) & 3))

static __device__ __forceinline__ unsigned short f2bf(float f) {
    union { float f; unsigned u; } v; v.f = f;
    unsigned r = v.u + 0x7FFFu + ((v.u >> 16) & 1u);
    return (unsigned short)(r >> 16);
}

static __device__ __forceinline__ void gload16(const void* g, void* l) {
    __builtin_amdgcn_global_load_lds(
        (const __attribute__((address_space(1))) unsigned int*)g,
        (__attribute__((address_space(3))) unsigned int*)l, 16, 0, 0);
}

// ---------------- styles: s = w @ (affW^T/sqrt(512)) + affb; st = m1*m2+m3 ----
__global__ __launch_bounds__(256) void stylesk(
    const float* __restrict__ w, const float* __restrict__ affW,
    const float* __restrict__ affb, float* __restrict__ styles)
{
    int bx = blockIdx.x, b = blockIdx.y;   // bx 0..31
    int lane = threadIdx.x & 63, wv = threadIdx.x >> 6;
    float wr[8];
    const float* wb = w + b * 512 + lane * 8;
#pragma unroll
    for (int r = 0; r < 8; ++r) wr[r] = wb[r];
    for (int ii = 0; ii < 4; ++ii) {
        int i = bx * 16 + wv * 4 + ii;
        float d[3];
#pragma unroll
        for (int jj = 0; jj < 3; ++jj) {
            const float* a = affW + (size_t)(jj * 512 + i) * 512 + lane * 8;
            float dd = 0.f;
#pragma unroll
            for (int r = 0; r < 8; ++r) dd += wr[r] * a[r];
            for (int off = 32; off; off >>= 1) dd += __shfl_xor(dd, off);
            d[jj] = dd;
        }
        if (lane == 0) {
            const float inv = 0.044194173824159216f; // 1/sqrt(512)
            float s0 = d[0] * inv + affb[i];
            float s1 = d[1] * inv + affb[512 + i];
            float s2 = d[2] * inv + affb[1024 + i];
            styles[b * 512 + i] = s0 * s1 + s2;
        }
    }
}

// ---------------- GroupNorm stats: one block per (b,group) -------------------
__global__ __launch_bounds__(256) void gnstats(
    const float* __restrict__ x, float* __restrict__ meanv, float* __restrict__ rstdv)
{
    int bx = blockIdx.x, t = threadIdx.x;
    const float4* p = (const float4*)(x + (size_t)bx * 65536);
    float s = 0.f, q = 0.f;
#pragma unroll 4
    for (int k = 0; k < 64; ++k) {
        float4 v = p[t + (k << 8)];
        s += v.x + v.y + v.z + v.w;
        q += v.x * v.x + v.y * v.y + v.z * v.z + v.w * v.w;
    }
    for (int off = 32; off; off >>= 1) { s += __shfl_xor(s, off); q += __shfl_xor(q, off); }
    __shared__ float rs[4], rq[4];
    if ((t & 63) == 0) { rs[t >> 6] = s; rq[t >> 6] = q; }
    __syncthreads();
    if (t == 0) {
        float S = rs[0] + rs[1] + rs[2] + rs[3];
        float Q = rq[0] + rq[1] + rq[2] + rq[3];
        float mu = S * (1.f / 65536.f);
        float var = Q * (1.f / 65536.f) - mu * mu;
        meanv[bx] = mu;
        rstdv[bx] = rsqrtf(var + 1e-5f);
    }
}

// ---------------- demod coefficients: block per co ---------------------------
__global__ __launch_bounds__(256) void dcoefk(
    const float* __restrict__ weight, const float* __restrict__ styles,
    float* __restrict__ dcoef)
{
    __shared__ float st2[8 * 512];
    __shared__ float red[32];
    int co = blockIdx.x, t = threadIdx.x;
    for (int i = t; i < 4096; i += 256) { float s = styles[i]; st2[i] = s * s; }
    __syncthreads();
    float p[8] = {0, 0, 0, 0, 0, 0, 0, 0};
#pragma unroll
    for (int half = 0; half < 2; ++half) {
        int ci = t * 2 + half;
        const float* wp = weight + ((size_t)co * 512 + ci) * 9;
        float wsq = 0.f;
#pragma unroll
        for (int k = 0; k < 9; ++k) wsq += wp[k] * wp[k];
#pragma unroll
        for (int b = 0; b < 8; ++b) p[b] += wsq * st2[b * 512 + ci];
    }
    int lane = t & 63, wv = t >> 6;
#pragma unroll
    for (int b = 0; b < 8; ++b) {
        float v = p[b];
        for (int off = 32; off; off >>= 1) v += __shfl_xor(v, off);
        if (lane == 0) red[wv * 8 + b] = v;
    }
    __syncthreads();
    if (t < 8) {
        float s = red[t] + red[8 + t] + red[16 + t] + red[24 + t];
        dcoef[t * 512 + co] = rsqrtf(s + 1e-8f);
    }
}

// ---------------- weight pack: [co][ci][3][3] f32 -> [co][tap][ci] bf16 ------
__global__ __launch_bounds__(256) void packk(
    const float* __restrict__ weight, unsigned short* __restrict__ wpk)
{
    __shared__ float ld[9 * 128];
    int co = blockIdx.x, c4 = blockIdx.y, t = threadIdx.x;
    const float* src = weight + (size_t)co * 4608 + c4 * 1152;
    for (int f = t; f < 1152; f += 256)
        ld[(f % 9) * 128 + (f / 9)] = src[f];
    __syncthreads();
    unsigned short* dst = wpk + (size_t)co * 4608 + c4 * 128;
    for (int f = t; f < 1152; f += 256) {
        int tap = f >> 7, ci = f & 127;
        dst[tap * 512 + ci] = f2bf(ld[tap * 128 + ci]);
    }
}

// ------- normalize + modulate + transpose to channel-last bf16 ---------------
// xm[b][pix][ci] = ((x - mu)*rstd*gnw + gnb) * styles  (bf16)
__global__ __launch_bounds__(256) void modpack(
    const float* __restrict__ x, const float* __restrict__ styles,
    const float* __restrict__ gnw, const float* __restrict__ gnb,
    const float* __restrict__ meanv, const float* __restrict__ rstdv,
    unsigned short* __restrict__ xm)
{
    __shared__ float sA[512], sB[512];
    __shared__ unsigned short tr[32 * 520];
    int t = threadIdx.x;
    int px0 = blockIdx.x * 32, b = blockIdx.y;
    for (int i = t; i < 512; i += 256) {
        int g = i >> 4;
        float mu = meanv[b * 32 + g], r = rstdv[b * 32 + g];
        float st = styles[b * 512 + i];
        float a = r * gnw[i];
        sA[i] = a * st;
        sB[i] = (gnb[i] - mu * a) * st;
    }
    __syncthreads();
    int p = t & 31, cb = t >> 5;
    const float* xb = x + (size_t)b * 512 * 4096 + px0 + p;
#pragma unroll 4
    for (int it = 0; it < 64; ++it) {
        int ci = cb + (it << 3);
        float v = xb[(size_t)ci * 4096];
        tr[p * 520 + ci] = f2bf(v * sA[ci] + sB[ci]);
    }
    __syncthreads();
    int gran = t & 63;
#pragma unroll
    for (int k = 0; k < 8; ++k) {
        int pl = k * 4 + (t >> 6);
        short8 v = *(const short8*)&tr[pl * 520 + gran * 8];
        *(short8*)&xm[((size_t)(b * 4096 + px0 + pl) << 9) + gran * 8] = v;
    }
}

// ---------------- implicit-GEMM 3x3 conv, 2-phase pipelined ------------------
// block: 512 thr (8 waves = 2m x 4n), tile 128 co x 512 pix (8 rows x 64 cols)
// phases p=0..47: (cc,dy); w dbuf 2x24576B, in dbuf 2x42240B  (133632 B dyn LDS)
__global__ __launch_bounds__(512, 2) void conv3(
    const unsigned short* __restrict__ xm, const unsigned short* __restrict__ wpk,
    const unsigned short* __restrict__ zp,
    const float* __restrict__ x, const float* __restrict__ noise,
    const float* __restrict__ bias, const float* __restrict__ gnw,
    const float* __restrict__ gnb, const float* __restrict__ gamma,
    const float* __restrict__ dcoef, const float* __restrict__ meanv,
    const float* __restrict__ rstdv, const float* __restrict__ nsp,
    float* __restrict__ out)
{
    extern __shared__ char smem[];
    char* wlds = smem;                 // [sel][dx3][co128][ci32] bf16
    char* ilds = smem + 49152;         // [sel][r10][c66][ci32] bf16

    const int tid = threadIdx.x, lane = tid & 63, wv = tid >> 6;
    const int ct = blockIdx.x, pt = blockIdx.y, b = blockIdx.z;
    const int co0 = ct * 128, h0 = pt * 8;
    const int wm = wv >> 2, wn = wv & 3;
    const int lm = lane & 15, lg = lane >> 4;

    // zero halo cols 0 and 65, all 10 rows, both buffers
    if (tid < 160) {
        int sel = tid / 80, rem = tid % 80;
        int r = rem >> 3, col = ((rem >> 2) & 1) * 65, g = rem & 3;
        *(short8*)(ilds + sel * 42240 + r * 4224 + col * 64 + g * 16) = (short8)0;
    }

    // staging descriptors (thread-fixed)
    const unsigned short* wsrc_fix[3]; int wdst_off[3];
#pragma unroll
    for (int q = 0; q < 3; ++q) {
        int k = q * 8 + wv;                 // 24 chunks of 1KB
        int id = k * 64 + lane;             // granule id
        int dxid = id >> 9, co = (id >> 2) & 127, g = (id & 3) ^ SWZ(co);
        wsrc_fix[q] = wpk + (size_t)(co0 + co) * 4608 + dxid * 512 + g * 8;
        wdst_off[q] = k * 1024;
    }
    const unsigned short* isrc_fix[5]; int idst_off[5];
#pragma unroll
    for (int q = 0; q < 5; ++q) {
        int k = q * 8 + wv;                 // 40 chunks of 1KB
        int r = k >> 2, chunk = k & 3;
        int idx = chunk * 64 + lane;
        int cimg = idx >> 2, gs = (idx & 3) ^ SWZ(cimg + 1);
        int imgrow = h0 - 1 + r;
        isrc_fix[q] = ((unsigned)imgrow < 64u)
            ? xm + (((size_t)(b * 4096 + imgrow * 64 + cimg)) << 9) + gs * 8
            : zp;
        idst_off[q] = r * 4224 + 64 + chunk * 1024;
    }

    int aoff[4];
#pragma unroll
    for (int m = 0; m < 4; ++m) {
        int col = wm * 64 + m * 16 + lm;
        aoff[m] = col * 64 + (lg ^ SWZ(col)) * 16;
    }
    int boff[3][4];
#pragma unroll
    for (int dx = 0; dx < 3; ++dx)
#pragma unroll
        for (int nc = 0; nc < 4; ++nc) {
            int c = nc * 16 + lm + dx;
            boff[dx][nc] = c * 64 + (lg ^ SWZ(c)) * 16;
        }

    f32x4 acc[4][8];
#pragma unroll
    for (int m = 0; m < 4; ++m)
#pragma unroll
        for (int n = 0; n < 8; ++n) acc[m][n] = (f32x4){0.f, 0.f, 0.f, 0.f};

    // prologue: stage w(cc=0,dy=0) -> wbuf0, in(cc=0) -> ibuf0
#pragma unroll
    for (int q = 0; q < 3; ++q) gload16(wsrc_fix[q], wlds + wdst_off[q]);
#pragma unroll
    for (int q = 0; q < 5; ++q) gload16(isrc_fix[q], ilds + idst_off[q]);
    __syncthreads();

    int cc = 0, dy = 0;
    for (int p = 0; p < 48; ++p) {
        int dyn = dy + 1, ccn = cc;
        if (dyn == 3) { dyn = 0; ccn = cc + 1; }
        // issue next-phase w stage (into the buffer NOT read this phase)
        if (p < 47) {
            int wadd = dyn * 1536 + ccn * 32;
            char* wd = wlds + ((p + 1) & 1) * 24576;
#pragma unroll
            for (int q = 0; q < 3; ++q) gload16(wsrc_fix[q] + wadd, wd + wdst_off[q]);
        }
        // issue in(cc+1) stage at dy==0 (into the buffer NOT read during cc)
        if (dy == 0 && cc < 15) {
            int iadd = (cc + 1) * 32;
            char* idp = ilds + ((cc + 1) & 1) * 42240;
#pragma unroll
            for (int q = 0; q < 5; ++q) gload16(isrc_fix[q] + iadd, idp + idst_off[q]);
        }
        // compute current phase
        char* wbase = wlds + (p & 1) * 24576;
        char* ibase = ilds + (cc & 1) * 42240 + (2 * wn + dy) * 4224;
#pragma unroll
        for (int dx = 0; dx < 3; ++dx) {
            short8 af[4], bv[8];
#pragma unroll
            for (int m = 0; m < 4; ++m)
                af[m] = *(const short8*)(wbase + dx * 8192 + aoff[m]);
#pragma unroll
            for (int n = 0; n < 8; ++n)
                bv[n] = *(const short8*)(ibase + (n >> 2) * 4224 + boff[dx][n & 3]);
#pragma unroll
            for (int m = 0; m < 4; ++m)
#pragma unroll
                for (int n = 0; n < 8; ++n)
                    acc[m][n] = __builtin_amdgcn_mfma_f32_16x16x32_bf16(
                        af[m], bv[n], acc[m][n], 0, 0, 0);
        }
        __syncthreads();   // drains vmcnt (stages) + lgkm; next phase safe
        dy = dyn; cc = ccn;
    }

    // epilogue: demod, noise, bias, lrelu*2*sqrt(2), layer-scale, residual, *sqrt(2)
    const float nsv = *nsp;
#pragma unroll
    for (int m = 0; m < 4; ++m) {
#pragma unroll
        for (int n = 0; n < 8; ++n) {
            int pix = (h0 + 2 * wn + (n >> 2)) * 64 + (n & 3) * 16 + lm;
            float nz = noise[b * 4096 + pix] * nsv;
#pragma unroll
            for (int j = 0; j < 4; ++j) {
                int co = co0 + wm * 64 + m * 16 + lg * 4 + j;
                int gidx = co >> 4;
                float v = acc[m][n][j] * dcoef[b * 512 + co] + nz + bias[co];
                float act = (v > 0.f ? v : 0.2f * v) * 2.8284271247461903f;
                float xv = x[((size_t)(b * 512 + co)) * 4096 + pix];
                float xn = (xv - meanv[b * 32 + gidx]) * rstdv[b * 32 + gidx] * gnw[co] + gnb[co];
                out[((size_t)(b * 512 + co)) * 4096 + pix] =
                    (gamma[co] * act + xn) * 1.4142135623730951f;
            }
        }
    }
}

extern "C" void kernel_launch(void* const* d_in, const int* in_sizes, int n_in,
                              void* d_out, int out_size, void* d_ws, size_t ws_size,
                              hipStream_t stream) {
    const float* x      = (const float*)d_in[0];
    const float* w      = (const float*)d_in[1];
    const float* noise  = (const float*)d_in[2];
    const float* weight = (const float*)d_in[3];
    const float* bias   = (const float*)d_in[4];
    const float* affW   = (const float*)d_in[5];
    const float* affb   = (const float*)d_in[6];
    const float* gnw    = (const float*)d_in[7];
    const float* gnb    = (const float*)d_in[8];
    const float* gamma  = (const float*)d_in[9];
    const float* nsp    = (const float*)d_in[10];
    float* out = (float*)d_out;

    char* ws = (char*)d_ws;
    float* styles = (float*)(ws + 0);            // 16384 B
    float* dcoef  = (float*)(ws + 16384);        // 16384 B
    float* meanv  = (float*)(ws + 32768);        // 1024 B
    float* rstdv  = (float*)(ws + 33792);        // 1024 B
    unsigned short* zp  = (unsigned short*)(ws + 34816);   // 4096 B zero page
    unsigned short* wpk = (unsigned short*)(ws + 38912);   // 4,718,592 B
    unsigned short* xm  = (unsigned short*)(ws + 4757504); // 33,554,432 B

    hipMemsetAsync(zp, 0, 4096, stream);

    // allow >64KB dynamic LDS for conv3 (idempotent; safe during capture)
    hipFuncSetAttribute(reinterpret_cast<const void*>(conv3),
                        hipFuncAttributeMaxDynamicSharedMemorySize, 135168);

    stylesk<<<dim3(32, 8), 256, 0, stream>>>(w, affW, affb, styles);
    gnstats<<<dim3(256), 256, 0, stream>>>(x, meanv, rstdv);
    packk<<<dim3(512, 4), 256, 0, stream>>>(weight, wpk);
    dcoefk<<<dim3(512), 256, 0, stream>>>(weight, styles, dcoef);
    modpack<<<dim3(128, 8), 256, 0, stream>>>(x, styles, gnw, gnb, meanv, rstdv, xm);
    conv3<<<dim3(4, 8, 8), 512, 133632, stream>>>(xm, wpk, zp, x, noise, bias, gnw, gnb,
                                                  gamma, dcoef, meanv, rstdv, nsp, out);
}

// Round 4
// 302.350 us; speedup vs baseline: 1.1152x; 1.0237x over previous
//
#include <hip/hip_runtime.h>
#include <hip/hip_bf16.h>

// B=8, CIN=512, COUT=512, RES=64, WDIM=512, K=3, GROUPS=32
typedef short short8 __attribute__((ext_vector_type(8)));
typedef float f32x4 __attribute__((ext_vector_type(4)));

#define SWZ(c) (((c) & 3) ^ (((c) >> 2) & 3))
#define UNROLL _Pragma("unroll")

static __device__ __forceinline__ unsigned short f2bf(float f) {
    union { float f; unsigned u; } v; v.f = f;
    unsigned r = v.u + 0x7FFFu + ((v.u >> 16) & 1u);
    return (unsigned short)(r >> 16);
}

static __device__ __forceinline__ void gload16(const void* g, void* l) {
    __builtin_amdgcn_global_load_lds(
        (const __attribute__((address_space(1))) unsigned int*)g,
        (__attribute__((address_space(3))) unsigned int*)l, 16, 0, 0);
}

// ============ prep1: gnstats (256) | stylesk (256) | packk (2048) | zp =======
__global__ __launch_bounds__(256) void prep1(
    const float* __restrict__ x, const float* __restrict__ w,
    const float* __restrict__ affW, const float* __restrict__ affb,
    const float* __restrict__ weight,
    float* __restrict__ styles, float* __restrict__ meanv,
    float* __restrict__ rstdv, unsigned short* __restrict__ wpk,
    unsigned short* __restrict__ zp)
{
    __shared__ float ld[9 * 128];
    __shared__ float rs[4], rq[4];
    const int bid = blockIdx.x, t = threadIdx.x;

    if (bid < 256) {                       // ---- GroupNorm stats, bx = bid
        const float4* p = (const float4*)(x + (size_t)bid * 65536);
        float s = 0.f, q = 0.f;
#pragma unroll 4
        for (int k = 0; k < 64; ++k) {
            float4 v = p[t + (k << 8)];
            s += v.x + v.y + v.z + v.w;
            q += v.x * v.x + v.y * v.y + v.z * v.z + v.w * v.w;
        }
        for (int off = 32; off; off >>= 1) { s += __shfl_xor(s, off); q += __shfl_xor(q, off); }
        if ((t & 63) == 0) { rs[t >> 6] = s; rq[t >> 6] = q; }
        __syncthreads();
        if (t == 0) {
            float S = rs[0] + rs[1] + rs[2] + rs[3];
            float Q = rq[0] + rq[1] + rq[2] + rq[3];
            float mu = S * (1.f / 65536.f);
            float var = Q * (1.f / 65536.f) - mu * mu;
            meanv[bid] = mu;
            rstdv[bid] = rsqrtf(var + 1e-5f);
        }
    } else if (bid < 512) {                // ---- styles
        int idx = bid - 256, bx = idx & 31, b = idx >> 5;
        int lane = t & 63, wv = t >> 6;
        float wr[8];
        const float* wb = w + b * 512 + lane * 8;
        UNROLL for (int r = 0; r < 8; ++r) wr[r] = wb[r];
        for (int ii = 0; ii < 4; ++ii) {
            int i = bx * 16 + wv * 4 + ii;
            float d[3];
            UNROLL for (int jj = 0; jj < 3; ++jj) {
                const float* a = affW + (size_t)(jj * 512 + i) * 512 + lane * 8;
                float dd = 0.f;
                UNROLL for (int r = 0; r < 8; ++r) dd += wr[r] * a[r];
                for (int off = 32; off; off >>= 1) dd += __shfl_xor(dd, off);
                d[jj] = dd;
            }
            if (lane == 0) {
                const float inv = 0.044194173824159216f; // 1/sqrt(512)
                float s0 = d[0] * inv + affb[i];
                float s1 = d[1] * inv + affb[512 + i];
                float s2 = d[2] * inv + affb[1024 + i];
                styles[b * 512 + i] = s0 * s1 + s2;
            }
        }
    } else if (bid < 2560) {               // ---- weight pack
        int idx = bid - 512, co = idx >> 2, c4 = idx & 3;
        const float* src = weight + (size_t)co * 4608 + c4 * 1152;
        for (int f = t; f < 1152; f += 256)
            ld[(f % 9) * 128 + (f / 9)] = src[f];
        __syncthreads();
        unsigned short* dst = wpk + (size_t)co * 4608 + c4 * 128;
        for (int f = t; f < 1152; f += 256) {
            int tap = f >> 7, ci = f & 127;
            dst[tap * 512 + ci] = f2bf(ld[tap * 128 + ci]);
        }
    } else {                               // ---- zero page
        *(short8*)&zp[t * 8] = (short8)0;
    }
}

// ============ prep2: dcoef (512) | modpack (1024) ============================
__global__ __launch_bounds__(256) void prep2(
    const float* __restrict__ x, const float* __restrict__ weight,
    const float* __restrict__ styles, const float* __restrict__ gnw,
    const float* __restrict__ gnb, const float* __restrict__ meanv,
    const float* __restrict__ rstdv,
    float* __restrict__ dcoef, unsigned short* __restrict__ xm)
{
    __shared__ float st2[8 * 512];
    __shared__ float red[32];
    __shared__ float sA[512], sB[512];
    __shared__ unsigned short tr[32 * 520];
    const int bid = blockIdx.x, t = threadIdx.x;

    if (bid < 512) {                       // ---- demod coefficients, co = bid
        int co = bid;
        for (int i = t; i < 4096; i += 256) { float s = styles[i]; st2[i] = s * s; }
        __syncthreads();
        float p[8] = {0, 0, 0, 0, 0, 0, 0, 0};
        UNROLL for (int half = 0; half < 2; ++half) {
            int ci = t * 2 + half;
            const float* wp = weight + ((size_t)co * 512 + ci) * 9;
            float wsq = 0.f;
            UNROLL for (int k = 0; k < 9; ++k) wsq += wp[k] * wp[k];
            UNROLL for (int b = 0; b < 8; ++b) p[b] += wsq * st2[b * 512 + ci];
        }
        int lane = t & 63, wv = t >> 6;
        UNROLL for (int b = 0; b < 8; ++b) {
            float v = p[b];
            for (int off = 32; off; off >>= 1) v += __shfl_xor(v, off);
            if (lane == 0) red[wv * 8 + b] = v;
        }
        __syncthreads();
        if (t < 8) {
            float s = red[t] + red[8 + t] + red[16 + t] + red[24 + t];
            dcoef[t * 512 + co] = rsqrtf(s + 1e-8f);
        }
    } else {                               // ---- normalize+modulate+transpose
        int idx = bid - 512, b = idx >> 7, px0 = (idx & 127) * 32;
        for (int i = t; i < 512; i += 256) {
            int g = i >> 4;
            float mu = meanv[b * 32 + g], r = rstdv[b * 32 + g];
            float st = styles[b * 512 + i];
            float a = r * gnw[i];
            sA[i] = a * st;
            sB[i] = (gnb[i] - mu * a) * st;
        }
        __syncthreads();
        int p = t & 31, cb = t >> 5;
        const float* xb = x + (size_t)b * 512 * 4096 + px0 + p;
#pragma unroll 4
        for (int it = 0; it < 64; ++it) {
            int ci = cb + (it << 3);
            float v = xb[(size_t)ci * 4096];
            tr[p * 520 + ci] = f2bf(v * sA[ci] + sB[ci]);
        }
        __syncthreads();
        int gran = t & 63;
        UNROLL for (int k = 0; k < 8; ++k) {
            int pl = k * 4 + (t >> 6);
            short8 v = *(const short8*)&tr[pl * 520 + gran * 8];
            *(short8*)&xm[((size_t)(b * 4096 + px0 + pl) << 9) + gran * 8] = v;
        }
    }
}

// ============ implicit-GEMM 3x3 conv, counted-vmcnt pipelined ================
// 512 thr (8 waves = 2m x 4n), tile 128co x 512pix (8 rows); 48 phases (cc,dy)
// wbuf: 3 slots x 24576B (slot = dy), ibuf: 2 x 42240B   => 158208 B dyn LDS
#define STAGE_W(SLOT, CC_, DY_)                                                 \
    { char* wd_ = wlds + (SLOT) * 24576; int wadd_ = (DY_) * 1536 + (CC_) * 32; \
      UNROLL for (int q = 0; q < 3; ++q)                                        \
          gload16(wsrc_fix[q] + wadd_, wd_ + wdst_off[q]); }

#define STAGE_I(CC_)                                                            \
    { char* id_ = ilds + ((CC_) & 1) * 42240; int iadd_ = (CC_) * 32;           \
      UNROLL for (int q = 0; q < 5; ++q)                                        \
          gload16(isrc_fix[q] + iadd_, id_ + idst_off[q]); }

#define PHASE(DY, CCSEL, VMN, STAGES_)                                          \
  {                                                                             \
    char* wbase = wlds + (DY) * 24576;                                          \
    char* ibase = ilds + (CCSEL) * 42240 + (2 * wn + (DY)) * 4224;              \
    short8 a0[4], b0[8], a1[4], b1[8], a2[4], b2[8];                            \
    UNROLL for (int m = 0; m < 4; ++m)                                          \
        a0[m] = *(const short8*)(wbase + aoff[m]);                              \
    UNROLL for (int n = 0; n < 8; ++n)                                          \
        b0[n] = *(const short8*)(ibase + (n >> 2) * 4224 + boff[0][n & 3]);     \
    STAGES_                                                                     \
    asm volatile("s_barrier" ::: "memory");                                     \
    UNROLL for (int m = 0; m < 4; ++m)                                          \
        a1[m] = *(const short8*)(wbase + 8192 + aoff[m]);                       \
    UNROLL for (int n = 0; n < 8; ++n)                                          \
        b1[n] = *(const short8*)(ibase + (n >> 2) * 4224 + boff[1][n & 3]);     \
    __builtin_amdgcn_s_setprio(1);                                              \
    UNROLL for (int m = 0; m < 4; ++m)                                          \
        UNROLL for (int n = 0; n < 8; ++n)                                      \
            acc[m][n] = __builtin_amdgcn_mfma_f32_16x16x32_bf16(                \
                a0[m], b0[n], acc[m][n], 0, 0, 0);                              \
    UNROLL for (int m = 0; m < 4; ++m)                                          \
        a2[m] = *(const short8*)(wbase + 16384 + aoff[m]);                      \
    UNROLL for (int n = 0; n < 8; ++n)                                          \
        b2[n] = *(const short8*)(ibase + (n >> 2) * 4224 + boff[2][n & 3]);     \
    UNROLL for (int m = 0; m < 4; ++m)                                          \
        UNROLL for (int n = 0; n < 8; ++n)                                      \
            acc[m][n] = __builtin_amdgcn_mfma_f32_16x16x32_bf16(                \
                a1[m], b1[n], acc[m][n], 0, 0, 0);                              \
    UNROLL for (int m = 0; m < 4; ++m)                                          \
        UNROLL for (int n = 0; n < 8; ++n)                                      \
            acc[m][n] = __builtin_amdgcn_mfma_f32_16x16x32_bf16(                \
                a2[m], b2[n], acc[m][n], 0, 0, 0);                              \
    __builtin_amdgcn_s_setprio(0);                                              \
    asm volatile("s_waitcnt vmcnt(" #VMN ")" ::: "memory");                     \
    asm volatile("s_barrier" ::: "memory");                                     \
  }

__global__ __launch_bounds__(512, 2) void conv3(
    const unsigned short* __restrict__ xm, const unsigned short* __restrict__ wpk,
    const unsigned short* __restrict__ zp,
    const float* __restrict__ x, const float* __restrict__ noise,
    const float* __restrict__ bias, const float* __restrict__ gnw,
    const float* __restrict__ gnb, const float* __restrict__ gamma,
    const float* __restrict__ dcoef, const float* __restrict__ meanv,
    const float* __restrict__ rstdv, const float* __restrict__ nsp,
    float* __restrict__ out)
{
    extern __shared__ char smem[];
    char* wlds = smem;                 // [slot3][dx3][co128][ci32] bf16
    char* ilds = smem + 73728;         // [sel2][r10][c66][ci32] bf16

    const int tid = threadIdx.x, lane = tid & 63, wv = tid >> 6;
    const int ct = blockIdx.x, pt = blockIdx.y, b = blockIdx.z;
    const int co0 = ct * 128, h0 = pt * 8;
    const int wm = wv >> 2, wn = wv & 3;
    const int lm = lane & 15, lg = lane >> 4;

    // zero halo cols 0 and 65, all 10 rows, both input buffers
    if (tid < 160) {
        int sel = tid / 80, rem = tid % 80;
        int r = rem >> 3, col = ((rem >> 2) & 1) * 65, g = rem & 3;
        *(short8*)(ilds + sel * 42240 + r * 4224 + col * 64 + g * 16) = (short8)0;
    }

    // staging descriptors (thread-fixed)
    const unsigned short* wsrc_fix[3]; int wdst_off[3];
    UNROLL for (int q = 0; q < 3; ++q) {
        int k = q * 8 + wv;                 // 24 chunks of 1KB per w slice
        int id = k * 64 + lane;
        int dxid = id >> 9, co = (id >> 2) & 127, g = (id & 3) ^ SWZ(co);
        wsrc_fix[q] = wpk + (size_t)(co0 + co) * 4608 + dxid * 512 + g * 8;
        wdst_off[q] = k * 1024;
    }
    const unsigned short* isrc_fix[5]; int idst_off[5];
    UNROLL for (int q = 0; q < 5; ++q) {
        int k = q * 8 + wv;                 // 40 chunks of 1KB per in slice
        int r = k >> 2, chunk = k & 3;
        int idx = chunk * 64 + lane;
        int cimg = idx >> 2, gs = (idx & 3) ^ SWZ(cimg + 1);
        int imgrow = h0 - 1 + r;
        isrc_fix[q] = ((unsigned)imgrow < 64u)
            ? xm + (((size_t)(b * 4096 + imgrow * 64 + cimg)) << 9) + gs * 8
            : zp;
        idst_off[q] = r * 4224 + 64 + chunk * 1024;
    }

    int aoff[4];
    UNROLL for (int m = 0; m < 4; ++m) {
        int col = wm * 64 + m * 16 + lm;
        aoff[m] = col * 64 + (lg ^ SWZ(col)) * 16;
    }
    int boff[3][4];
    UNROLL for (int dx = 0; dx < 3; ++dx)
        UNROLL for (int nc = 0; nc < 4; ++nc) {
            int c = nc * 16 + lm + dx;
            boff[dx][nc] = c * 64 + (lg ^ SWZ(c)) * 16;
        }

    f32x4 acc[4][8];
    UNROLL for (int m = 0; m < 4; ++m)
        UNROLL for (int n = 0; n < 8; ++n) acc[m][n] = (f32x4){0.f, 0.f, 0.f, 0.f};

    // prologue: w(0,0)->slot0, i(0)->ibuf0, w(0,1)->slot1; publish w0+i0
    STAGE_W(0, 0, 0)
    STAGE_I(0)
    STAGE_W(1, 0, 1)
    asm volatile("s_waitcnt lgkmcnt(0)" ::: "memory");   // halo ds_writes done
    asm volatile("s_waitcnt vmcnt(3)" ::: "memory");     // w(0,0)+i(0) landed
    asm volatile("s_barrier" ::: "memory");

#pragma unroll 1
    for (int cc = 0; cc < 15; ++cc) {
        const int cs = cc & 1;
        PHASE(0, cs, 8, STAGE_W(2, cc, 2) STAGE_I(cc + 1))
        PHASE(1, cs, 8, STAGE_W(0, cc + 1, 0))
        PHASE(2, cs, 3, STAGE_W(1, cc + 1, 1))
    }
    PHASE(0, 1, 3, STAGE_W(2, 15, 2))
    PHASE(1, 1, 0, {})
    PHASE(2, 1, 0, {})

    // epilogue: demod, noise, bias, lrelu*2*sqrt(2), layer-scale, residual, *sqrt(2)
    const float nsv = *nsp;
    UNROLL for (int m = 0; m < 4; ++m) {
        UNROLL for (int n = 0; n < 8; ++n) {
            int pix = (h0 + 2 * wn + (n >> 2)) * 64 + (n & 3) * 16 + lm;
            float nz = noise[b * 4096 + pix] * nsv;
            UNROLL for (int j = 0; j < 4; ++j) {
                int co = co0 + wm * 64 + m * 16 + lg * 4 + j;
                int gidx = co >> 4;
                float v = acc[m][n][j] * dcoef[b * 512 + co] + nz + bias[co];
                float act = (v > 0.f ? v : 0.2f * v) * 2.8284271247461903f;
                float xv = x[((size_t)(b * 512 + co)) * 4096 + pix];
                float xn = (xv - meanv[b * 32 + gidx]) * rstdv[b * 32 + gidx] * gnw[co] + gnb[co];
                out[((size_t)(b * 512 + co)) * 4096 + pix] =
                    (gamma[co] * act + xn) * 1.4142135623730951f;
            }
        }
    }
}

extern "C" void kernel_launch(void* const* d_in, const int* in_sizes, int n_in,
                              void* d_out, int out_size, void* d_ws, size_t ws_size,
                              hipStream_t stream) {
    const float* x      = (const float*)d_in[0];
    const float* w      = (const float*)d_in[1];
    const float* noise  = (const float*)d_in[2];
    const float* weight = (const float*)d_in[3];
    const float* bias   = (const float*)d_in[4];
    const float* affW   = (const float*)d_in[5];
    const float* affb   = (const float*)d_in[6];
    const float* gnw    = (const float*)d_in[7];
    const float* gnb    = (const float*)d_in[8];
    const float* gamma  = (const float*)d_in[9];
    const float* nsp    = (const float*)d_in[10];
    float* out = (float*)d_out;

    char* ws = (char*)d_ws;
    float* styles = (float*)(ws + 0);            // 16384 B
    float* dcoef  = (float*)(ws + 16384);        // 16384 B
    float* meanv  = (float*)(ws + 32768);        // 1024 B
    float* rstdv  = (float*)(ws + 33792);        // 1024 B
    unsigned short* zp  = (unsigned short*)(ws + 34816);   // 4096 B zero page
    unsigned short* wpk = (unsigned short*)(ws + 38912);   // 4,718,592 B
    unsigned short* xm  = (unsigned short*)(ws + 4757504); // 33,554,432 B

    hipFuncSetAttribute(reinterpret_cast<const void*>(conv3),
                        hipFuncAttributeMaxDynamicSharedMemorySize, 158208);

    prep1<<<dim3(2561), 256, 0, stream>>>(x, w, affW, affb, weight,
                                          styles, meanv, rstdv, wpk, zp);
    prep2<<<dim3(1536), 256, 0, stream>>>(x, weight, styles, gnw, gnb,
                                          meanv, rstdv, dcoef, xm);
    conv3<<<dim3(4, 8, 8), 512, 158208, stream>>>(xm, wpk, zp, x, noise, bias, gnw, gnb,
                                                  gamma, dcoef, meanv, rstdv, nsp, out);
}

// Round 5
// 299.175 us; speedup vs baseline: 1.1271x; 1.0106x over previous
//
#include <hip/hip_runtime.h>
#include <hip/hip_bf16.h>

// B=8, CIN=512, COUT=512, RES=64, WDIM=512, K=3, GROUPS=32
typedef short short8 __attribute__((ext_vector_type(8)));
typedef float f32x16 __attribute__((ext_vector_type(16)));

#define SWZ(c) (((c) & 3) ^ (((c) >> 2) & 3))
#define UNROLL _Pragma("unroll")

static __device__ __forceinline__ unsigned short f2bf(float f) {
    union { float f; unsigned u; } v; v.f = f;
    unsigned r = v.u + 0x7FFFu + ((v.u >> 16) & 1u);
    return (unsigned short)(r >> 16);
}

static __device__ __forceinline__ void gload16(const void* g, void* l) {
    __builtin_amdgcn_global_load_lds(
        (const __attribute__((address_space(1))) unsigned int*)g,
        (__attribute__((address_space(3))) unsigned int*)l, 16, 0, 0);
}

// ============ prep1: gnstats(256) | styles(256) | pack(512) | zp(1) ==========
// pack: weight [co][ci512][3][3] f32 -> wpk2 [tap9][k16step32][co512][ci16] bf16
__global__ __launch_bounds__(256) void prep1(
    const float* __restrict__ x, const float* __restrict__ w,
    const float* __restrict__ affW, const float* __restrict__ affb,
    const float* __restrict__ weight,
    float* __restrict__ styles, float* __restrict__ meanv,
    float* __restrict__ rstdv, unsigned short* __restrict__ wpk2,
    unsigned short* __restrict__ zp)
{
    __shared__ float ld[4608];
    __shared__ float rs[4], rq[4];
    const int bid = blockIdx.x, t = threadIdx.x;

    if (bid < 256) {                       // ---- GroupNorm stats, (b,g) = bid
        const float4* p = (const float4*)(x + (size_t)bid * 65536);
        float s = 0.f, q = 0.f;
#pragma unroll 4
        for (int k = 0; k < 64; ++k) {
            float4 v = p[t + (k << 8)];
            s += v.x + v.y + v.z + v.w;
            q += v.x * v.x + v.y * v.y + v.z * v.z + v.w * v.w;
        }
        for (int off = 32; off; off >>= 1) { s += __shfl_xor(s, off); q += __shfl_xor(q, off); }
        if ((t & 63) == 0) { rs[t >> 6] = s; rq[t >> 6] = q; }
        __syncthreads();
        if (t == 0) {
            float S = rs[0] + rs[1] + rs[2] + rs[3];
            float Q = rq[0] + rq[1] + rq[2] + rq[3];
            float mu = S * (1.f / 65536.f);
            float var = Q * (1.f / 65536.f) - mu * mu;
            meanv[bid] = mu;
            rstdv[bid] = rsqrtf(var + 1e-5f);
        }
    } else if (bid < 512) {                // ---- styles
        int idx = bid - 256, bx = idx & 31, b = idx >> 5;
        int lane = t & 63, wv = t >> 6;
        float wr[8];
        const float* wb = w + b * 512 + lane * 8;
        UNROLL for (int r = 0; r < 8; ++r) wr[r] = wb[r];
        for (int ii = 0; ii < 4; ++ii) {
            int i = bx * 16 + wv * 4 + ii;
            float d[3];
            UNROLL for (int jj = 0; jj < 3; ++jj) {
                const float* a = affW + (size_t)(jj * 512 + i) * 512 + lane * 8;
                float dd = 0.f;
                UNROLL for (int r = 0; r < 8; ++r) dd += wr[r] * a[r];
                for (int off = 32; off; off >>= 1) dd += __shfl_xor(dd, off);
                d[jj] = dd;
            }
            if (lane == 0) {
                const float inv = 0.044194173824159216f; // 1/sqrt(512)
                float s0 = d[0] * inv + affb[i];
                float s1 = d[1] * inv + affb[512 + i];
                float s2 = d[2] * inv + affb[1024 + i];
                styles[b * 512 + i] = s0 * s1 + s2;
            }
        }
    } else if (bid < 1024) {               // ---- weight pack, co = bid-512
        int co = bid - 512;
        const float* src = weight + (size_t)co * 4608;
        for (int f = t; f < 4608; f += 256)
            ld[(f % 9) * 512 + (f / 9)] = src[f];
        __syncthreads();
        for (int idx = t; idx < 4608; idx += 256) {
            int tap = idx >> 9, ci = idx & 511;
            int kk = ci >> 4, c16 = ci & 15;
            wpk2[((size_t)(tap * 32 + kk) * 512 + co) * 16 + c16] =
                f2bf(ld[tap * 512 + ci]);
        }
    } else {                               // ---- zero page
        *(short8*)&zp[t * 8] = (short8)0;
    }
}

// ============ prep2: dcoef (512) | modpack (1024) ============================
__global__ __launch_bounds__(256) void prep2(
    const float* __restrict__ x, const float* __restrict__ weight,
    const float* __restrict__ styles, const float* __restrict__ gnw,
    const float* __restrict__ gnb, const float* __restrict__ meanv,
    const float* __restrict__ rstdv,
    float* __restrict__ dcoef, unsigned short* __restrict__ xm)
{
    __shared__ float st2[8 * 512];
    __shared__ float red[32];
    __shared__ float sA[512], sB[512];
    __shared__ unsigned short tr[32 * 520];
    const int bid = blockIdx.x, t = threadIdx.x;

    if (bid < 512) {                       // ---- demod coefficients, co = bid
        int co = bid;
        for (int i = t; i < 4096; i += 256) { float s = styles[i]; st2[i] = s * s; }
        __syncthreads();
        float p[8] = {0, 0, 0, 0, 0, 0, 0, 0};
        UNROLL for (int half = 0; half < 2; ++half) {
            int ci = t * 2 + half;
            const float* wp = weight + ((size_t)co * 512 + ci) * 9;
            float wsq = 0.f;
            UNROLL for (int k = 0; k < 9; ++k) wsq += wp[k] * wp[k];
            UNROLL for (int b = 0; b < 8; ++b) p[b] += wsq * st2[b * 512 + ci];
        }
        int lane = t & 63, wv = t >> 6;
        UNROLL for (int b = 0; b < 8; ++b) {
            float v = p[b];
            for (int off = 32; off; off >>= 1) v += __shfl_xor(v, off);
            if (lane == 0) red[wv * 8 + b] = v;
        }
        __syncthreads();
        if (t < 8) {
            float s = red[t] + red[8 + t] + red[16 + t] + red[24 + t];
            dcoef[t * 512 + co] = rsqrtf(s + 1e-8f);
        }
    } else {                               // ---- normalize+modulate+transpose
        int idx = bid - 512, b = idx >> 7, px0 = (idx & 127) * 32;
        for (int i = t; i < 512; i += 256) {
            int g = i >> 4;
            float mu = meanv[b * 32 + g], r = rstdv[b * 32 + g];
            float st = styles[b * 512 + i];
            float a = r * gnw[i];
            sA[i] = a * st;
            sB[i] = (gnb[i] - mu * a) * st;
        }
        __syncthreads();
        int p = t & 31, cb = t >> 5;
        const float* xb = x + (size_t)b * 512 * 4096 + px0 + p;
#pragma unroll 4
        for (int it = 0; it < 64; ++it) {
            int ci = cb + (it << 3);
            float v = xb[(size_t)ci * 4096];
            tr[p * 520 + ci] = f2bf(v * sA[ci] + sB[ci]);
        }
        __syncthreads();
        int gran = t & 63;
        UNROLL for (int k = 0; k < 8; ++k) {
            int pl = k * 4 + (t >> 6);
            short8 v = *(const short8*)&tr[pl * 520 + gran * 8];
            *(short8*)&xm[((size_t)(b * 4096 + px0 + pl) << 9) + gran * 8] = v;
        }
    }
}

// ============ implicit-GEMM 3x3 conv: A(weights) direct global->VGPR =========
// 512 thr (8 waves = 2m x 4n); block tile 128co x 512pix (8 rows x 64 cols)
// wave tile 64co x 128pix = 2m x 4n of 32x32 MFMA; one barrier per ci-chunk cc.
// LDS: input only, dbuf 2 x [10r][66c][ci32] bf16 = 84480 B.
#define STAGE_I(CC_)                                                            \
    { char* id_ = ilds + ((CC_) & 1) * 42240; int iadd_ = (CC_) * 32;           \
      UNROLL for (int q = 0; q < 5; ++q)                                        \
          gload16(isrc_fix[q] + iadd_, id_ + idst_off[q]); }

__global__ __launch_bounds__(512, 2) void conv3(
    const unsigned short* __restrict__ xm, const unsigned short* __restrict__ wpk2,
    const unsigned short* __restrict__ zp,
    const float* __restrict__ x, const float* __restrict__ noise,
    const float* __restrict__ bias, const float* __restrict__ gnw,
    const float* __restrict__ gnb, const float* __restrict__ gamma,
    const float* __restrict__ dcoef, const float* __restrict__ meanv,
    const float* __restrict__ rstdv, const float* __restrict__ nsp,
    float* __restrict__ out)
{
    extern __shared__ char ilds[];     // [sel2][r10][c66][ci32] bf16

    const int tid = threadIdx.x, lane = tid & 63, wv = tid >> 6;
    const int ct = blockIdx.x, pt = blockIdx.y, b = blockIdx.z;
    const int co0 = ct * 128, h0 = pt * 8;
    const int wm = wv >> 2, wn = wv & 3;

    // zero halo cols 0 and 65, all 10 rows, both input buffers
    if (tid < 160) {
        int sel = tid / 80, rem = tid % 80;
        int r = rem >> 3, col = ((rem >> 2) & 1) * 65, g = rem & 3;
        *(short8*)(ilds + sel * 42240 + r * 4224 + col * 64 + g * 16) = (short8)0;
    }

    // input staging descriptors (thread-fixed)
    const unsigned short* isrc_fix[5]; int idst_off[5];
    UNROLL for (int q = 0; q < 5; ++q) {
        int k = q * 8 + wv;                 // 40 chunks of 1KB per cc-slice
        int r = k >> 2, chunk = k & 3;
        int idx = chunk * 64 + lane;
        int cimg = idx >> 2, gs = (idx & 3) ^ SWZ(cimg + 1);
        int imgrow = h0 - 1 + r;
        isrc_fix[q] = ((unsigned)imgrow < 64u)
            ? xm + (((size_t)(b * 4096 + imgrow * 64 + cimg)) << 9) + gs * 8
            : zp;
        idst_off[q] = r * 4224 + 64 + chunk * 1024;
    }

    // A-fragment per-lane base (ushort units):
    // wpk2 offset = ((tap*32 + kk)*512 + co)*16 + ci16
    const unsigned short* wA = wpk2
        + (size_t)(co0 + wm * 64 + (lane & 31)) * 16 + (lane >> 5) * 8;

    // B ds_read byte offsets: c = ch*32 + (lane&31) + dx, granule G'=(2s+lg2)^SWZ(c)
    int bo[2][3][2];
    UNROLL for (int ch = 0; ch < 2; ++ch)
        UNROLL for (int dx = 0; dx < 3; ++dx) {
            int c = ch * 32 + (lane & 31) + dx;
            UNROLL for (int s = 0; s < 2; ++s)
                bo[ch][dx][s] = c * 64 + (((s * 2 + (lane >> 5)) ^ SWZ(c)) * 16);
        }

    f32x16 acc[2][4];
    UNROLL for (int m = 0; m < 2; ++m)
        UNROLL for (int n = 0; n < 4; ++n) acc[m][n] = (f32x16)(0.0f);

    // prologue: stage input(0); preload A(cc=0, tap0); publish
    STAGE_I(0)
    short8 a0q[4];
    UNROLL for (int m = 0; m < 2; ++m)
        UNROLL for (int s = 0; s < 2; ++s)
            a0q[m * 2 + s] = *(const short8*)(wA + s * 8192 + m * 512);
    asm volatile("s_waitcnt vmcnt(0) lgkmcnt(0)" ::: "memory");
    asm volatile("s_barrier" ::: "memory");

#pragma unroll 1
    for (int cc = 0; cc < 16; ++cc) {
        if (cc < 15) STAGE_I(cc + 1)
        const unsigned short* wAc = wA + cc * 16384;
        const unsigned short* wAn = wA + (cc < 15 ? cc + 1 : 15) * 16384;
        char* ib = ilds + (cc & 1) * 42240;
        UNROLL for (int t = 0; t < 9; ++t) {
            const int dy = t / 3, dx = t % 3;
            // prefetch A for next tap (or tap0 of next cc)
            const unsigned short* wT =
                (t < 8) ? (wAc + (size_t)(t + 1) * 262144) : wAn;
            short8 a1q[4];
            UNROLL for (int m = 0; m < 2; ++m)
                UNROLL for (int s = 0; s < 2; ++s)
                    a1q[m * 2 + s] = *(const short8*)(wT + s * 8192 + m * 512);
            // B fragments from LDS
            char* r0 = ib + (2 * wn + dy) * 4224;
            short8 bv[8];
            UNROLL for (int nt = 0; nt < 4; ++nt)
                UNROLL for (int s = 0; s < 2; ++s)
                    bv[nt * 2 + s] = *(const short8*)
                        (r0 + (nt >> 1) * 4224 + bo[nt & 1][dx][s]);
            __builtin_amdgcn_s_setprio(1);
            UNROLL for (int s = 0; s < 2; ++s)
                UNROLL for (int m = 0; m < 2; ++m)
                    UNROLL for (int nt = 0; nt < 4; ++nt)
                        acc[m][nt] = __builtin_amdgcn_mfma_f32_32x32x16_bf16(
                            a0q[m * 2 + s], bv[nt * 2 + s], acc[m][nt], 0, 0, 0);
            __builtin_amdgcn_s_setprio(0);
            UNROLL for (int q = 0; q < 4; ++q) a0q[q] = a1q[q];
        }
        // stages are >=5 loads older than the newest 4 A-prefetches -> retired
        asm volatile("s_waitcnt vmcnt(4)" ::: "memory");
        asm volatile("s_barrier" ::: "memory");
    }

    // epilogue: demod, noise, bias, lrelu*2*sqrt(2), layer-scale, residual, *sqrt(2)
    const float nsv = *nsp;
    const int lg2 = lane >> 5;
    float nzv[4]; int pixv[4];
    UNROLL for (int nt = 0; nt < 4; ++nt) {
        pixv[nt] = (h0 + 2 * wn + (nt >> 1)) * 64 + (nt & 1) * 32 + (lane & 31);
        nzv[nt] = noise[b * 4096 + pixv[nt]] * nsv;
    }
    UNROLL for (int m = 0; m < 2; ++m) {
        UNROLL for (int r = 0; r < 16; ++r) {
            int co = co0 + wm * 64 + m * 32 + (r & 3) + 8 * (r >> 2) + 4 * lg2;
            int gidx = co >> 4;
            float dc = dcoef[b * 512 + co], bs = bias[co], gm = gamma[co];
            float a = rstdv[b * 32 + gidx] * gnw[co];
            float bsh = gnb[co] - meanv[b * 32 + gidx] * a;
            const float* xrow = x + ((size_t)(b * 512 + co)) * 4096;
            float* orow = out + ((size_t)(b * 512 + co)) * 4096;
            UNROLL for (int nt = 0; nt < 4; ++nt) {
                float v = acc[m][nt][r] * dc + nzv[nt] + bs;
                float act = (v > 0.f ? v : 0.2f * v) * 2.8284271247461903f;
                float xn = xrow[pixv[nt]] * a + bsh;
                orow[pixv[nt]] = (gm * act + xn) * 1.4142135623730951f;
            }
        }
    }
}

extern "C" void kernel_launch(void* const* d_in, const int* in_sizes, int n_in,
                              void* d_out, int out_size, void* d_ws, size_t ws_size,
                              hipStream_t stream) {
    const float* x      = (const float*)d_in[0];
    const float* w      = (const float*)d_in[1];
    const float* noise  = (const float*)d_in[2];
    const float* weight = (const float*)d_in[3];
    const float* bias   = (const float*)d_in[4];
    const float* affW   = (const float*)d_in[5];
    const float* affb   = (const float*)d_in[6];
    const float* gnw    = (const float*)d_in[7];
    const float* gnb    = (const float*)d_in[8];
    const float* gamma  = (const float*)d_in[9];
    const float* nsp    = (const float*)d_in[10];
    float* out = (float*)d_out;

    char* ws = (char*)d_ws;
    float* styles = (float*)(ws + 0);            // 16384 B
    float* dcoef  = (float*)(ws + 16384);        // 16384 B
    float* meanv  = (float*)(ws + 32768);        // 1024 B
    float* rstdv  = (float*)(ws + 33792);        // 1024 B
    unsigned short* zp   = (unsigned short*)(ws + 34816);   // 4096 B zero page
    unsigned short* wpk2 = (unsigned short*)(ws + 38912);   // 4,718,592 B
    unsigned short* xm   = (unsigned short*)(ws + 4757504); // 33,554,432 B

    hipFuncSetAttribute(reinterpret_cast<const void*>(conv3),
                        hipFuncAttributeMaxDynamicSharedMemorySize, 84480);

    prep1<<<dim3(1025), 256, 0, stream>>>(x, w, affW, affb, weight,
                                          styles, meanv, rstdv, wpk2, zp);
    prep2<<<dim3(1536), 256, 0, stream>>>(x, weight, styles, gnw, gnb,
                                          meanv, rstdv, dcoef, xm);
    conv3<<<dim3(4, 8, 8), 512, 84480, stream>>>(xm, wpk2, zp, x, noise, bias,
                                                 gnw, gnb, gamma, dcoef,
                                                 meanv, rstdv, nsp, out);
}